// Round 3
// baseline (330.191 us; speedup 1.0000x reference)
//
#include <hip/hip_runtime.h>
#include <hip/hip_bf16.h>
#include <stdint.h>

// ---------------------------------------------------------------------------
// XFMultiHeadAttention: B=4, S=2048, D=1024, H=16, depth=64.
// I/O f32, compute bf16 MFMA. Pipeline:
//   scan(mask->gather idx) ; transpose4(W) ;
//   fused QKV GEMM (all z: f32 A, reg-prefetch + cvt; B async16; dbuf LDS;
//                   counted-vmcnt barriers) -> Qh / Kc(swz) / Vc(sigma+swz) ;
//   zero_tails ; flash(compacted keys, fixed-max softmax) -> ctx(=Qh) ;
//   out GEMM (dbuf 2-phase) -> d_out
// ws (24MB): WT4(8MB) + Qh/ctx(16MB) + gidx(32KB) + nb(16B).
// Kc,Vc (16MB bf16 each) live in d_out (32MB f32), dead before out_gemm.
// Compaction is EXACT (masked rows never computed).
// Kc layout: row s, col = ((dp>>3 ^ (s&7))<<3)|(dp&7)           [bank swizzle]
// Vc layout: row d, within-64-tile col = swz(sigma(off), d):
//   sigma(off) = ((off&15)<<2)|(off>>4) ; then unit-XOR by (d&7)
// flash stages LINEARLY via global_load_lds and applies the same XOR on read.
// K-loop pipeline (qkv): per step s —
//   issueB(s+1)->Bs[nx] ; compute(cb) ; cvt+ds_write A(s+1)->As[nx] ;
//   [sched_barrier] loadA(s+2)->regs ; s_waitcnt vmcnt(4) ; s_barrier
// vmcnt retires IN ORDER: the 2 B-loads (older) retire, the 4 A-loads stay
// in flight across the barrier -> A has ~1.5 steps of latency cover.
// ---------------------------------------------------------------------------

#define S_LEN 2048
#define NHEAD 16
#define DEPTH 64
#define DMODEL 1024

typedef __bf16 bf16x8 __attribute__((ext_vector_type(8)));
typedef float f32x4 __attribute__((ext_vector_type(4)));
typedef uint16_t u16x8 __attribute__((ext_vector_type(8)));
typedef uint16_t u16x4 __attribute__((ext_vector_type(4)));

#if __has_builtin(__builtin_amdgcn_exp2f)
#define EXP2F(x) __builtin_amdgcn_exp2f(x)   // bare v_exp_f32 (flush-to-zero ok)
#else
#define EXP2F(x) __builtin_exp2f(x)
#endif

__device__ __forceinline__ uint16_t f2bf(float x) {
    __hip_bfloat16 h = __float2bfloat16(x);  // RNE
    union { __hip_bfloat16 h; uint16_t u; } v; v.h = h; return v.u;
}
__device__ __forceinline__ u16x8 pack8(f32x4 a, f32x4 b) {
    u16x8 r;
#pragma unroll
    for (int i = 0; i < 4; ++i) { r[i] = f2bf(a[i]); r[i + 4] = f2bf(b[i]); }
    return r;
}
// async 16B global->LDS (dest = wave-uniform base + lane*16)  [m97 pattern]
__device__ __forceinline__ void async16(const void* g, void* l) {
    __builtin_amdgcn_global_load_lds((__attribute__((address_space(1))) void*)(g),
                                     (__attribute__((address_space(3))) void*)(l),
                                     16, 0, 0);
}

// ---------------------------------------------------------------------------
// Mask scan: per batch, gidx[b][s'] = original row of s'-th unmasked key; nb[b].
// ---------------------------------------------------------------------------
__global__ void mask_scan(const float* __restrict__ mask, int* __restrict__ gidx,
                          int* __restrict__ nb) {
    __shared__ int part[256];
    const int b = blockIdx.x, tid = threadIdx.x;
    int flags[8], cnt = 0;
#pragma unroll
    for (int i = 0; i < 8; ++i) {
        flags[i] = (mask[b * S_LEN + tid * 8 + i] == 0.0f) ? 1 : 0;
        cnt += flags[i];
    }
    part[tid] = cnt;
    __syncthreads();
    for (int st = 1; st < 256; st <<= 1) {
        int v = (tid >= st) ? part[tid - st] : 0;
        __syncthreads();
        part[tid] += v;
        __syncthreads();
    }
    int run = part[tid] - cnt;  // exclusive offset
#pragma unroll
    for (int i = 0; i < 8; ++i) {
        if (flags[i]) { gidx[b * S_LEN + run] = tid * 8 + i; ++run; }
    }
    if (tid == 255) nb[b] = part[255];
}

// ---------------------------------------------------------------------------
// Weight transpose + bf16 cast: WT4[z][n][k] = bf16(W_z[k][n]); z=Wq,Wk,Wv,Wo
// ---------------------------------------------------------------------------
__global__ void transpose4(const float* __restrict__ w0, const float* __restrict__ w1,
                           const float* __restrict__ w2, const float* __restrict__ w3,
                           uint16_t* __restrict__ dst) {
    __shared__ uint16_t tile[32][33];
    const float* src = (blockIdx.z == 0) ? w0 : (blockIdx.z == 1) ? w1
                     : (blockIdx.z == 2) ? w2 : w3;
    uint16_t* d = dst + (size_t)blockIdx.z * DMODEL * DMODEL;
    int bx = blockIdx.x * 32, by = blockIdx.y * 32;
    int x = threadIdx.x, y0 = threadIdx.y;
#pragma unroll
    for (int i = 0; i < 4; ++i) {
        int y = y0 + i * 8;
        tile[y][x] = f2bf(src[(size_t)(by + y) * DMODEL + bx + x]);
    }
    __syncthreads();
#pragma unroll
    for (int i = 0; i < 4; ++i) {
        int y = y0 + i * 8;
        d[(size_t)(bx + y) * DMODEL + by + x] = tile[x][y];
    }
}

// ---------------------------------------------------------------------------
// Zero the padding tail of Kc rows / Vc cols in [nb, ceil64(nb)).
// ---------------------------------------------------------------------------
__global__ void zero_tails(const int* __restrict__ nb, uint16_t* __restrict__ Kc,
                           uint16_t* __restrict__ Vc) {
    const int bh = blockIdx.x, b = bh >> 4, t = threadIdx.x;
    const int nbv = nb[b];
    const int end = ((nbv + 63) >> 6) << 6;
    const int tail = end - nbv;  // 0..63
    for (int i = t; i < tail * 64; i += 256) {
        int r = nbv + (i >> 6), c = i & 63;
        Kc[((size_t)bh * S_LEN + r) * DEPTH + c] = 0;
    }
    for (int i = t; i < tail * 64; i += 256) {
        int s = nbv + (i >> 6), d = i & 63;
        int off = s & 63;
        int c1 = ((off & 15) << 2) | (off >> 4);
        int c2 = ((((c1 >> 3) ^ (d & 7)) & 7) << 3) | (c1 & 7);
        Vc[((size_t)bh * DEPTH + d) * S_LEN + (s & ~63) + c2] = 0;
    }
}

// ---------------------------------------------------------------------------
// Fused QKV NT GEMM: out_z = X_z @ W_z^T + bias_z.  128x128 tile, BK=32,
// 4 waves, dbuf LDS, counted-vmcnt pipeline. All z read f32 A rows
// (z=0: q linear; z=1: k gathered; z=2: v gathered), cvt to bf16 in regs.
// ---------------------------------------------------------------------------
__global__ __launch_bounds__(256, 3)
void qkv_gemm(const float* __restrict__ qf, const float* __restrict__ kf,
              const float* __restrict__ vf, const uint16_t* __restrict__ WT4,
              const float* __restrict__ bq, const float* __restrict__ bk,
              const float* __restrict__ bv, uint16_t* __restrict__ Qh,
              uint16_t* __restrict__ Kc, uint16_t* __restrict__ Vc,
              const int* __restrict__ gidx, const int* __restrict__ nb) {
    const int z = blockIdx.z;
    // XCD swizzle: 8 n-tiles of one A-row-panel land on one XCD (bijective)
    const int fid = blockIdx.x + 8 * blockIdx.y;                  // 0..511
    const int n0 = ((fid >> 3) & 7) * 128;
    const int m0 = ((((fid >> 6) << 3)) | (fid & 7)) * 128;
    const int b_ = m0 >> 11;
    int nbv = 0x7FFFFFFF;
    if (z >= 1) {
        nbv = nb[b_];
        if ((m0 & 2047) >= nbv) return;  // block-uniform early exit
    }

    __shared__ __align__(16) uint16_t As[2][128 * 32];
    __shared__ __align__(16) uint16_t Bs[2][128 * 32];

    const int t = threadIdx.x;
    const int lane = t & 63, quad = lane >> 4, l16 = lane & 15;
    const int w = t >> 6, wm = w >> 1, wn = w & 1;
    const int K = DMODEL;

    const int r_ld = lane >> 2;        // row within 16-row chunk (B async path)
    const int c_ld = (lane & 3) * 8;   // 8-col group
    const uint16_t* gB = WT4 + (size_t)z * DMODEL * DMODEL + (size_t)(n0 + r_ld) * K + c_ld;
    const float* bias = (z == 0) ? bq : (z == 1) ? bk : bv;

    // A staging coords: thread t -> row t>>1, cols (t&1)*16..+15 (16 floats)
    const int srow = t >> 1, scol = (t & 1) * 16;
    const float* Af32;
    if (z == 0) {
        Af32 = qf + (size_t)(m0 + srow) * K + scol;
    } else {
        int sp = (m0 & 2047) + srow;
        int rs = (sp < nbv) ? gidx[(b_ << 11) + sp] : 0;  // clamp: dummy row 0
        Af32 = ((z == 1) ? kf : vf) + ((size_t)(b_ << 11) + rs) * K + scol;
    }

    f32x4 acc[4][4];
    const f32x4 z4 = {0.f, 0.f, 0.f, 0.f};
#pragma unroll
    for (int mt = 0; mt < 4; ++mt)
#pragma unroll
        for (int nt = 0; nt < 4; ++nt) acc[mt][nt] = z4;

    f32x4 fa[4];  // A-prefetch registers (static indices only)
    auto loadA = [&](int kc) {
#pragma unroll
        for (int i = 0; i < 4; ++i) fa[i] = *(const f32x4*)(Af32 + kc + i * 4);
    };
    uint16_t* wA0 = &As[0][srow * 32 + scol];
    uint16_t* wA1 = &As[1][srow * 32 + scol];
    auto writeA = [&](int buf) {
        uint16_t* d = buf ? wA1 : wA0;
        *(u16x8*)d = pack8(fa[0], fa[1]);
        *(u16x8*)(d + 8) = pack8(fa[2], fa[3]);
    };
    auto issueB = [&](int kc, int buf) {
#pragma unroll
        for (int i = 0; i < 2; ++i) {
            int c = w * 2 + i;  // chunk 0..7 = rows 16c..16c+15
            async16(gB + (size_t)(c * 16) * K + kc, &Bs[buf][c * 512]);
        }
    };
    auto compute = [&](int buf) {
        bf16x8 af[4], bfr[4];
#pragma unroll
        for (int mt = 0; mt < 4; ++mt)
            af[mt] = *(const bf16x8*)&As[buf][(wm * 64 + mt * 16 + l16) * 32 + quad * 8];
#pragma unroll
        for (int nt = 0; nt < 4; ++nt)
            bfr[nt] = *(const bf16x8*)&Bs[buf][(wn * 64 + nt * 16 + l16) * 32 + quad * 8];
#pragma unroll
        for (int mt = 0; mt < 4; ++mt)
#pragma unroll
            for (int nt = 0; nt < 4; ++nt)
                acc[mt][nt] = __builtin_amdgcn_mfma_f32_16x16x32_bf16(af[mt], bfr[nt],
                                                                      acc[mt][nt], 0, 0, 0);
    };

    // prologue: tile 0 staged, A(1) in flight
    issueB(0, 0);
    loadA(0);
    writeA(0);                         // compiler-inserted waitcnt drains A(0)
    __builtin_amdgcn_sched_barrier(0);
    loadA(32);                         // A(1) -> regs, stays in flight
    asm volatile("s_waitcnt vmcnt(4) lgkmcnt(0)" ::: "memory");
    __builtin_amdgcn_s_barrier();
    __builtin_amdgcn_sched_barrier(0);

    for (int s = 0; s < 32; ++s) {
        const int cb = s & 1;
        if (s < 31) issueB((s + 1) * 32, cb ^ 1);   // 2 vmem, oldest this step
        compute(cb);
        if (s < 31) {
            writeA(cb ^ 1);                          // consume A(s+1) (vmcnt(2))
            __builtin_amdgcn_sched_barrier(0);
            if (s < 30) {
                loadA((s + 2) * 32);                 // 4 vmem, newest -> survive
                __builtin_amdgcn_sched_barrier(0);
                asm volatile("s_waitcnt vmcnt(4) lgkmcnt(0)" ::: "memory");
            } else {
                asm volatile("s_waitcnt vmcnt(0) lgkmcnt(0)" ::: "memory");
            }
            __builtin_amdgcn_s_barrier();
            __builtin_amdgcn_sched_barrier(0);
        }
    }

    // epilogue: C/D layout col=lane&15, row=quad*4+reg
#pragma unroll
    for (int nt = 0; nt < 4; ++nt) {
        int col = n0 + wn * 64 + nt * 16 + l16;
        float bval = bias[col];
        int h = col >> 6, dp = col & 63;
#pragma unroll
        for (int mt = 0; mt < 4; ++mt) {
#pragma unroll
            for (int r = 0; r < 4; ++r) {
                int row = m0 + wm * 64 + mt * 16 + quad * 4 + r;
                float val = acc[mt][nt][r] + bval;
                int b = row >> 11, s = row & 2047;
                if (z == 0) {
                    Qh[(((size_t)(b * NHEAD + h)) * S_LEN + s) * DEPTH + dp] = f2bf(val);
                } else if (z == 1) {
                    if (s < nbv) {
                        int c2 = ((((dp >> 3) ^ (s & 7)) & 7) << 3) | (dp & 7);
                        Kc[(((size_t)(b * NHEAD + h)) * S_LEN + s) * DEPTH + c2] = f2bf(val);
                    }
                } else {
                    if (s < nbv) {
                        int off = s & 63;
                        int c1 = ((off & 15) << 2) | (off >> 4);                  // sigma
                        int c2 = ((((c1 >> 3) ^ (dp & 7)) & 7) << 3) | (c1 & 7);  // bank swz
                        Vc[(((size_t)(b * NHEAD + h)) * DEPTH + dp) * S_LEN
                           + (s & ~63) + c2] = f2bf(val);
                    }
                }
            }
        }
    }
}

// ---------------------------------------------------------------------------
// Out GEMM: d_out = ctx @ Wo^T + bo.  A bf16 head-split + B via async16,
// dbuf LDS 2-phase (stage(s+1) before compute(s), one barrier/step).
// ---------------------------------------------------------------------------
__global__ __launch_bounds__(256, 3)
void out_gemm(const uint16_t* __restrict__ ctx, const uint16_t* __restrict__ Wt,
              const float* __restrict__ bias, float* __restrict__ outp) {
    const int fid = blockIdx.x + 8 * blockIdx.y;
    const int n0 = ((fid >> 3) & 7) * 128;
    const int m0 = ((((fid >> 6) << 3)) | (fid & 7)) * 128;

    __shared__ __align__(16) uint16_t As[2][128 * 32];
    __shared__ __align__(16) uint16_t Bs[2][128 * 32];

    const int t = threadIdx.x;
    const int lane = t & 63, quad = lane >> 4, l16 = lane & 15;
    const int w = t >> 6, wm = w >> 1, wn = w & 1;
    const int K = DMODEL;

    const int r_ld = lane >> 2;
    const int c_ld = (lane & 3) * 8;
    const uint16_t* gB = Wt + (size_t)(n0 + r_ld) * K + c_ld;

    int row0 = m0 + (w * 2 + 0) * 16 + r_ld;
    int row1 = row0 + 16;
    const uint16_t* pA0 = ctx + ((size_t)((row0 >> 11) * NHEAD) * S_LEN + (row0 & 2047)) * DEPTH + c_ld;
    const uint16_t* pA1 = ctx + ((size_t)((row1 >> 11) * NHEAD) * S_LEN + (row1 & 2047)) * DEPTH + c_ld;

    auto stage = [&](int kc, int buf) {
#pragma unroll
        for (int i = 0; i < 2; ++i) {
            int c = w * 2 + i;
            async16(gB + (size_t)(c * 16) * K + kc, &Bs[buf][c * 512]);
        }
        size_t aoff = ((size_t)(kc >> 6) << 17) + (kc & 63);  // head stride 2^17
        async16(pA0 + aoff, &As[buf][(w * 2 + 0) * 512]);
        async16(pA1 + aoff, &As[buf][(w * 2 + 1) * 512]);
    };

    f32x4 acc[4][4];
    const f32x4 z4 = {0.f, 0.f, 0.f, 0.f};
#pragma unroll
    for (int mt = 0; mt < 4; ++mt)
#pragma unroll
        for (int nt = 0; nt < 4; ++nt) acc[mt][nt] = z4;

    stage(0, 0);
    __syncthreads();

    for (int s = 0; s < 32; ++s) {
        const int cb = s & 1;
        if (s < 31) stage((s + 1) * 32, cb ^ 1);
        {
            bf16x8 af[4], bfr[4];
#pragma unroll
            for (int mt = 0; mt < 4; ++mt)
                af[mt] = *(const bf16x8*)&As[cb][(wm * 64 + mt * 16 + l16) * 32 + quad * 8];
#pragma unroll
            for (int nt = 0; nt < 4; ++nt)
                bfr[nt] = *(const bf16x8*)&Bs[cb][(wn * 64 + nt * 16 + l16) * 32 + quad * 8];
#pragma unroll
            for (int mt = 0; mt < 4; ++mt)
#pragma unroll
                for (int nt = 0; nt < 4; ++nt)
                    acc[mt][nt] = __builtin_amdgcn_mfma_f32_16x16x32_bf16(af[mt], bfr[nt],
                                                                          acc[mt][nt], 0, 0, 0);
        }
        if (s < 31) __syncthreads();
    }

#pragma unroll
    for (int nt = 0; nt < 4; ++nt) {
        int col = n0 + wn * 64 + nt * 16 + l16;
        float bval = bias[col];
#pragma unroll
        for (int mt = 0; mt < 4; ++mt) {
#pragma unroll
            for (int r = 0; r < 4; ++r) {
                int row = m0 + wm * 64 + mt * 16 + quad * 4 + r;
                outp[(size_t)row * DMODEL + col] = acc[mt][nt][r] + bval;
            }
        }
    }
}

// ---------------------------------------------------------------------------
// Flash attention over COMPACTED keys, fixed-max softmax (m=12, exp2-domain).
// Grid (16 q-tiles, 64 bh), XCD-swizzled. 256 thr (4 waves), 32 q-rows/wave.
// LDS 41KB -> 3 blocks/CU. One __syncthreads per tile; prefetch in flight.
// ---------------------------------------------------------------------------
__global__ __launch_bounds__(256, 3)
void flash_attn(const uint16_t* __restrict__ Qh, const uint16_t* __restrict__ Kc,
                const uint16_t* __restrict__ Vc, const int* __restrict__ nb,
                uint16_t* __restrict__ ctx) {
    __shared__ __align__(16) uint16_t Ks[2][64 * 64];
    __shared__ __align__(16) uint16_t Vs[2][64 * 64];
    __shared__ __align__(16) uint16_t Ps[4][16 * 72];

    const int t = threadIdx.x;
    const int w = t >> 6, lane = t & 63, quad = lane >> 4, l16 = lane & 15;
    // XCD swizzle: 16 q-tiles sharing one bh's K/V land on one XCD (bijective)
    const int fid = blockIdx.x + 16 * blockIdx.y;                // 0..1023
    const int q0 = ((fid >> 3) & 15) * 128;
    const int bh = ((fid >> 7) << 3) | (fid & 7);
    const int b = bh >> 4;
    const int nbv = nb[b];
    const int ntiles = (nbv + 63) >> 6;

    const int srow8 = lane >> 3, scol8 = (lane & 7) * 8;
    const uint16_t* pKn = Kc + ((size_t)bh * S_LEN + w * 16 + srow8) * DEPTH + scol8;
    const uint16_t* pVn = Vc + ((size_t)bh * DEPTH + w * 16 + srow8) * S_LEN + scol8;
    uint16_t* dK0 = &Ks[0][w * 16 * 64];
    uint16_t* dK1 = &Ks[1][w * 16 * 64];
    uint16_t* dV0 = &Vs[0][w * 16 * 64];
    uint16_t* dV1 = &Vs[1][w * 16 * 64];

    bf16x8 aq[2][2];
#pragma unroll
    for (int mt = 0; mt < 2; ++mt)
#pragma unroll
        for (int kc = 0; kc < 2; ++kc)
            aq[mt][kc] = *(const bf16x8*)(Qh + ((size_t)bh * S_LEN + q0 + w * 32 + mt * 16 + l16) * DEPTH
                                          + kc * 32 + quad * 8);

    float lrow[2][4];
    f32x4 Oacc[2][4];
    const f32x4 z4 = {0.f, 0.f, 0.f, 0.f};
#pragma unroll
    for (int mt = 0; mt < 2; ++mt)
#pragma unroll
        for (int r = 0; r < 4; ++r) lrow[mt][r] = 0.f;
#pragma unroll
    for (int mt = 0; mt < 2; ++mt)
#pragma unroll
        for (int nt = 0; nt < 4; ++nt) Oacc[mt][nt] = z4;

    const float C2 = 0.18033688f;
    const float M2 = 17.312340f;
    const int swzk = l16 & 7;

    async16(pKn, dK0); async16(pKn + 8 * DEPTH, dK0 + 8 * 64);
    async16(pVn, dV0); async16(pVn + 8 * S_LEN, dV0 + 8 * 64);
    pKn += 64 * DEPTH; pVn += 64;
    __syncthreads();

    for (int kt = 0; kt < ntiles; ++kt) {
        const int cur = kt & 1;
        if (kt + 1 < ntiles) {
            uint16_t* dK = cur ? dK0 : dK1;
            uint16_t* dV = cur ? dV0 : dV1;
            async16(pKn, dK); async16(pKn + 8 * DEPTH, dK + 8 * 64);
            async16(pVn, dV); async16(pVn + 8 * S_LEN, dV + 8 * 64);
            pKn += 64 * DEPTH; pVn += 64;
        }
        const uint16_t* ksrc = cur ? &Ks[1][0] : &Ks[0][0];
        const uint16_t* vsrc = cur ? &Vs[1][0] : &Vs[0][0];
        const int k0 = kt * 64;

        float pen[4];
#pragma unroll
        for (int nt = 0; nt < 4; ++nt)
            pen[nt] = (k0 + nt * 16 + l16 < nbv) ? -M2 : -2e9f;

        f32x4 sacc[2][4];
#pragma unroll
        for (int mt = 0; mt < 2; ++mt)
#pragma unroll
            for (int nt = 0; nt < 4; ++nt) sacc[mt][nt] = z4;
        __builtin_amdgcn_s_setprio(1);
#pragma unroll
        for (int kc = 0; kc < 2; ++kc) {
#pragma unroll
            for (int nt = 0; nt < 4; ++nt) {
                bf16x8 bk = *(const bf16x8*)&ksrc[(nt * 16 + l16) * 64 + (((kc * 4 + quad) ^ swzk) << 3)];
#pragma unroll
                for (int mt = 0; mt < 2; ++mt)
                    sacc[mt][nt] = __builtin_amdgcn_mfma_f32_16x16x32_bf16(aq[mt][kc], bk,
                                                                           sacc[mt][nt], 0, 0, 0);
            }
        }
        __builtin_amdgcn_s_setprio(0);

        bf16x8 bvr[2][4];
#pragma unroll
        for (int kc = 0; kc < 2; ++kc)
#pragma unroll
            for (int nt = 0; nt < 4; ++nt)
                bvr[kc][nt] = *(const bf16x8*)&vsrc[(nt * 16 + l16) * 64 + (((kc * 4 + quad) ^ swzk) << 3)];

#pragma unroll
        for (int mt = 0; mt < 2; ++mt) {
#pragma unroll
            for (int r = 0; r < 4; ++r) {
                float p0 = EXP2F(fmaf(sacc[mt][0][r], C2, pen[0]));
                float p1 = EXP2F(fmaf(sacc[mt][1][r], C2, pen[1]));
                float p2 = EXP2F(fmaf(sacc[mt][2][r], C2, pen[2]));
                float p3 = EXP2F(fmaf(sacc[mt][3][r], C2, pen[3]));
                lrow[mt][r] += (p0 + p1) + (p2 + p3);
                u16x4 pk;
                pk[0] = f2bf(p0); pk[1] = f2bf(p1); pk[2] = f2bf(p2); pk[3] = f2bf(p3);
                *(u16x4*)&Ps[w][(quad * 4 + r) * 72 + l16 * 4] = pk;
            }
            __builtin_amdgcn_s_setprio(1);
#pragma unroll
            for (int kc = 0; kc < 2; ++kc) {
                bf16x8 ap = *(const bf16x8*)&Ps[w][l16 * 72 + kc * 32 + quad * 8];
#pragma unroll
                for (int nt = 0; nt < 4; ++nt)
                    Oacc[mt][nt] = __builtin_amdgcn_mfma_f32_16x16x32_bf16(ap, bvr[kc][nt],
                                                                           Oacc[mt][nt], 0, 0, 0);
            }
            __builtin_amdgcn_s_setprio(0);
        }
        __syncthreads();
    }

#pragma unroll
    for (int mt = 0; mt < 2; ++mt) {
#pragma unroll
        for (int r = 0; r < 4; ++r) {
            float rs = lrow[mt][r];
            rs += __shfl_xor(rs, 1);
            rs += __shfl_xor(rs, 2);
            rs += __shfl_xor(rs, 4);
            rs += __shfl_xor(rs, 8);
            float inv = 1.0f / rs;
            int srow = q0 + w * 32 + mt * 16 + quad * 4 + r;
            size_t base = ((size_t)bh * S_LEN + srow) * DEPTH;
#pragma unroll
            for (int nt = 0; nt < 4; ++nt)
                ctx[base + nt * 16 + l16] = f2bf(Oacc[mt][nt][r] * inv);
        }
    }
}

// ---------------------------------------------------------------------------
extern "C" void kernel_launch(void* const* d_in, const int* in_sizes, int n_in,
                              void* d_out, int out_size, void* d_ws, size_t ws_size,
                              hipStream_t stream) {
    const float* v    = (const float*)d_in[0];
    const float* k    = (const float*)d_in[1];
    const float* q    = (const float*)d_in[2];
    const float* mask = (const float*)d_in[3];
    const float* Wq   = (const float*)d_in[4];
    const float* bq   = (const float*)d_in[5];
    const float* Wk   = (const float*)d_in[6];
    const float* bk   = (const float*)d_in[7];
    const float* Wv   = (const float*)d_in[8];
    const float* bv   = (const float*)d_in[9];
    const float* Wo   = (const float*)d_in[10];
    const float* bo   = (const float*)d_in[11];

    // ws: WT4(8MB) + Qh(16MB) + gidx(32KB) + nb(16B) = ~24MB
    char* p = (char*)d_ws;
    uint16_t* WT4 = (uint16_t*)p; p += (size_t)4 * DMODEL * DMODEL * 2;
    uint16_t* Qh  = (uint16_t*)p; p += (size_t)64 * S_LEN * DEPTH * 2;
    int* gidx     = (int*)p;      p += (size_t)4 * S_LEN * 4;
    int* nb       = (int*)p;      p += 16;

    // Kc, Vc (16MB bf16 each) in d_out — dead before out_gemm writes f32 out
    uint16_t* Kc = (uint16_t*)d_out;
    uint16_t* Vc = Kc + (size_t)64 * S_LEN * DEPTH;

    mask_scan<<<4, 256, 0, stream>>>(mask, gidx, nb);
    transpose4<<<dim3(32, 32, 4), dim3(32, 8), 0, stream>>>(Wq, Wk, Wv, Wo, WT4);

    qkv_gemm<<<dim3(8, 64, 3), 256, 0, stream>>>(q, k, v, WT4, bq, bk, bv,
                                                 Qh, Kc, Vc, gidx, nb);
    zero_tails<<<64, 256, 0, stream>>>(nb, Kc, Vc);

    flash_attn<<<dim3(16, 64), 256, 0, stream>>>(Qh, Kc, Vc, nb, Qh /*ctx*/);

    out_gemm<<<dim3(8, 64), 256, 0, stream>>>(Qh, WT4 + (size_t)3 * DMODEL * DMODEL,
                                              bo, (float*)d_out);
}

// Round 4
// 312.048 us; speedup vs baseline: 1.0581x; 1.0581x over previous
//
#include <hip/hip_runtime.h>
#include <hip/hip_bf16.h>
#include <stdint.h>

// ---------------------------------------------------------------------------
// XFMultiHeadAttention: B=4, S=2048, D=1024, H=16, depth=64.
// I/O f32, compute bf16 MFMA. Pipeline:
//   scan(mask->gather idx) ; transpose4(W) ;
//   fused QKV GEMM (depth-2 counted-vmcnt pipeline: A via 3 reg-sets,
//                   B via LDS tri-buffer) -> Qh / Kc(swz) / Vc(sigma+swz) ;
//   zero_tails ; flash(compacted keys, fixed-max softmax) -> ctx(=Qh) ;
//   out GEMM (tri-buffer A+B, counted vmcnt) -> d_out
// ws (24MB): WT4(8MB) + Qh/ctx(16MB) + gidx(32KB) + nb(16B).
// Kc,Vc (16MB bf16 each) live in d_out (32MB f32), dead before out_gemm.
// Compaction is EXACT (masked rows never computed).
// Kc layout: row s, col = ((dp>>3 ^ (s&7))<<3)|(dp&7)           [bank swizzle]
// Vc layout: row d, within-64-tile col = swz(sigma(off), d):
//   sigma(off) = ((off&15)<<2)|(off>>4) ; then unit-XOR by (d&7)
// flash stages LINEARLY via global_load_lds and applies the same XOR on read.
//
// qkv K-loop schedule (step s, full unroll, all indices literal):
//   issueB(s+2)->Bs[(s+2)%3]            (2 vmem)
//   compute(As[s&1], Bs[s%3])           (ds_read + 16 MFMA, setprio-wrapped)
//   writeA(As[(s&1)^1] <- fa[(s+1)%3])  (compiler waits A(s+1): 2-step-old)
//   loadA(s+3) -> fa[s%3]               (4 vmem)
//   s_waitcnt vmcnt(10) lgkmcnt(0) ; s_barrier
// vmcnt(10): newer-than-B(s+1) = A(s+2)4 + B(s+2)2 + A(s+3)4. B(s+1) retires
// (1.5-2 step cover); A loads stay in flight across the barrier (2-step cover).
// Bias/gidx loads are fenced OLDEST so counts stay exact.
// ---------------------------------------------------------------------------

#define S_LEN 2048
#define NHEAD 16
#define DEPTH 64
#define DMODEL 1024

typedef __bf16 bf16x8 __attribute__((ext_vector_type(8)));
typedef float f32x4 __attribute__((ext_vector_type(4)));
typedef uint16_t u16x8 __attribute__((ext_vector_type(8)));
typedef uint16_t u16x4 __attribute__((ext_vector_type(4)));

#if __has_builtin(__builtin_amdgcn_exp2f)
#define EXP2F(x) __builtin_amdgcn_exp2f(x)   // bare v_exp_f32 (flush-to-zero ok)
#else
#define EXP2F(x) __builtin_exp2f(x)
#endif

__device__ __forceinline__ uint16_t f2bf(float x) {
    __hip_bfloat16 h = __float2bfloat16(x);  // RNE
    union { __hip_bfloat16 h; uint16_t u; } v; v.h = h; return v.u;
}
__device__ __forceinline__ u16x8 pack8(f32x4 a, f32x4 b) {
    u16x8 r;
#pragma unroll
    for (int i = 0; i < 4; ++i) { r[i] = f2bf(a[i]); r[i + 4] = f2bf(b[i]); }
    return r;
}
// async 16B global->LDS (dest = wave-uniform base + lane*16)  [m97 pattern]
__device__ __forceinline__ void async16(const void* g, void* l) {
    __builtin_amdgcn_global_load_lds((__attribute__((address_space(1))) void*)(g),
                                     (__attribute__((address_space(3))) void*)(l),
                                     16, 0, 0);
}

// ---------------------------------------------------------------------------
// Mask scan: per batch, gidx[b][s'] = original row of s'-th unmasked key; nb[b].
// ---------------------------------------------------------------------------
__global__ void mask_scan(const float* __restrict__ mask, int* __restrict__ gidx,
                          int* __restrict__ nb) {
    __shared__ int part[256];
    const int b = blockIdx.x, tid = threadIdx.x;
    int flags[8], cnt = 0;
#pragma unroll
    for (int i = 0; i < 8; ++i) {
        flags[i] = (mask[b * S_LEN + tid * 8 + i] == 0.0f) ? 1 : 0;
        cnt += flags[i];
    }
    part[tid] = cnt;
    __syncthreads();
    for (int st = 1; st < 256; st <<= 1) {
        int v = (tid >= st) ? part[tid - st] : 0;
        __syncthreads();
        part[tid] += v;
        __syncthreads();
    }
    int run = part[tid] - cnt;  // exclusive offset
#pragma unroll
    for (int i = 0; i < 8; ++i) {
        if (flags[i]) { gidx[b * S_LEN + run] = tid * 8 + i; ++run; }
    }
    if (tid == 255) nb[b] = part[255];
}

// ---------------------------------------------------------------------------
// Weight transpose + bf16 cast: WT4[z][n][k] = bf16(W_z[k][n]); z=Wq,Wk,Wv,Wo
// ---------------------------------------------------------------------------
__global__ void transpose4(const float* __restrict__ w0, const float* __restrict__ w1,
                           const float* __restrict__ w2, const float* __restrict__ w3,
                           uint16_t* __restrict__ dst) {
    __shared__ uint16_t tile[32][33];
    const float* src = (blockIdx.z == 0) ? w0 : (blockIdx.z == 1) ? w1
                     : (blockIdx.z == 2) ? w2 : w3;
    uint16_t* d = dst + (size_t)blockIdx.z * DMODEL * DMODEL;
    int bx = blockIdx.x * 32, by = blockIdx.y * 32;
    int x = threadIdx.x, y0 = threadIdx.y;
#pragma unroll
    for (int i = 0; i < 4; ++i) {
        int y = y0 + i * 8;
        tile[y][x] = f2bf(src[(size_t)(by + y) * DMODEL + bx + x]);
    }
    __syncthreads();
#pragma unroll
    for (int i = 0; i < 4; ++i) {
        int y = y0 + i * 8;
        d[(size_t)(bx + y) * DMODEL + by + x] = tile[x][y];
    }
}

// ---------------------------------------------------------------------------
// Zero the padding tail of Kc rows / Vc cols in [nb, ceil64(nb)).
// ---------------------------------------------------------------------------
__global__ void zero_tails(const int* __restrict__ nb, uint16_t* __restrict__ Kc,
                           uint16_t* __restrict__ Vc) {
    const int bh = blockIdx.x, b = bh >> 4, t = threadIdx.x;
    const int nbv = nb[b];
    const int end = ((nbv + 63) >> 6) << 6;
    const int tail = end - nbv;  // 0..63
    for (int i = t; i < tail * 64; i += 256) {
        int r = nbv + (i >> 6), c = i & 63;
        Kc[((size_t)bh * S_LEN + r) * DEPTH + c] = 0;
    }
    for (int i = t; i < tail * 64; i += 256) {
        int s = nbv + (i >> 6), d = i & 63;
        int off = s & 63;
        int c1 = ((off & 15) << 2) | (off >> 4);
        int c2 = ((((c1 >> 3) ^ (d & 7)) & 7) << 3) | (c1 & 7);
        Vc[((size_t)bh * DEPTH + d) * S_LEN + (s & ~63) + c2] = 0;
    }
}

// ---------------------------------------------------------------------------
// Fused QKV NT GEMM, depth-2 counted-vmcnt pipeline. 128x128 tile, BK=32,
// 4 waves. A: f32 rows (z=0 q linear; z=1 k gathered; z=2 v gathered),
// 3 register sets, cvt->bf16, conflict-free linear LDS writes (t*16B).
// B: WT4 bf16 via async16, LDS tri-buffer.
// ---------------------------------------------------------------------------
__global__ __launch_bounds__(256, 3)
void qkv_gemm(const float* __restrict__ qf, const float* __restrict__ kf,
              const float* __restrict__ vf, const uint16_t* __restrict__ WT4,
              const float* __restrict__ bq, const float* __restrict__ bk,
              const float* __restrict__ bv, uint16_t* __restrict__ Qh,
              uint16_t* __restrict__ Kc, uint16_t* __restrict__ Vc,
              const int* __restrict__ gidx, const int* __restrict__ nb) {
    const int z = blockIdx.z;
    // XCD swizzle: 8 n-tiles of one A-row-panel land on one XCD (bijective)
    const int fid = blockIdx.x + 8 * blockIdx.y;                  // 0..511
    const int n0 = ((fid >> 3) & 7) * 128;
    const int m0 = ((((fid >> 6) << 3)) | (fid & 7)) * 128;
    const int b_ = m0 >> 11;
    int nbv = 0x7FFFFFFF;
    if (z >= 1) {
        nbv = nb[b_];
        if ((m0 & 2047) >= nbv) return;  // block-uniform early exit
    }

    __shared__ __align__(16) uint16_t As[2][128 * 32];
    __shared__ __align__(16) uint16_t Bs[3][128 * 32];

    const int t = threadIdx.x;
    const int lane = t & 63, quad = lane >> 4, l16 = lane & 15;
    const int w = t >> 6, wm = w >> 1, wn = w & 1;
    const int K = DMODEL;

    const int r_ld = lane >> 2;        // row within 16-row chunk (B async path)
    const int c_ld = (lane & 3) * 8;   // 8-col group
    const uint16_t* gB = WT4 + (size_t)z * DMODEL * DMODEL + (size_t)(n0 + r_ld) * K + c_ld;
    const float* bias = (z == 0) ? bq : (z == 1) ? bk : bv;

    // A map: thread t handles rows (t>>2) and 64+(t>>2), cols (t&3)*8..+7.
    // LDS write: one b128 at byte t*16 (+4KB for row-group b) — conflict-free.
    const float* pAa;
    const float* pAb;
    if (z == 0) {
        pAa = qf + (size_t)(m0 + (t >> 2)) * K + (t & 3) * 8;
        pAb = pAa + (size_t)64 * K;
    } else {
        const float* src = (z == 1) ? kf : vf;
        int spa = (m0 & 2047) + (t >> 2);
        int spb = spa + 64;
        int ra = (spa < nbv) ? gidx[(b_ << 11) + spa] : 0;  // clamp: dummy row 0
        int rb = (spb < nbv) ? gidx[(b_ << 11) + spb] : 0;
        pAa = src + ((size_t)(b_ << 11) + ra) * K + (t & 3) * 8;
        pAb = src + ((size_t)(b_ << 11) + rb) * K + (t & 3) * 8;
    }
    // fence: gidx loads retired (address dep) before any pipeline vmem issues
    asm volatile("" ::: "memory");

    f32x4 acc[4][4];
    const f32x4 z4 = {0.f, 0.f, 0.f, 0.f};
#pragma unroll
    for (int mt = 0; mt < 4; ++mt)
#pragma unroll
        for (int nt = 0; nt < 4; ++nt) acc[mt][nt] = z4;

    f32x4 fA0[4], fA1[4], fA2[4];  // 3 prefetch sets (A(k) lives in set k%3)

#define SEL(SET) ((SET) == 0 ? fA0 : (SET) == 1 ? fA1 : fA2)
#define LOADA(KC, SET) do {                                         \
        f32x4* c_ = SEL(SET);                                       \
        c_[0] = *(const f32x4*)(pAa + (KC));                        \
        c_[1] = *(const f32x4*)(pAa + (KC) + 4);                    \
        c_[2] = *(const f32x4*)(pAb + (KC));                        \
        c_[3] = *(const f32x4*)(pAb + (KC) + 4);                    \
    } while (0)
#define WRITEA(ABUF, SET) do {                                      \
        f32x4* c_ = SEL(SET);                                       \
        uint16_t* d_ = &As[(ABUF)][0] + t * 8;                      \
        *(u16x8*)d_ = pack8(c_[0], c_[1]);                          \
        *(u16x8*)(d_ + 2048) = pack8(c_[2], c_[3]);                 \
    } while (0)
#define ISSUEB(KC, BBUF) do {                                       \
        async16(gB + (size_t)((w * 2 + 0) * 16) * K + (KC),         \
                &Bs[(BBUF)][(w * 2 + 0) * 512]);                    \
        async16(gB + (size_t)((w * 2 + 1) * 16) * K + (KC),         \
                &Bs[(BBUF)][(w * 2 + 1) * 512]);                    \
    } while (0)
#define COMPUTE(ABUF, BBUF) do {                                    \
        bf16x8 af[4], bfr[4];                                       \
        _Pragma("unroll")                                           \
        for (int mt = 0; mt < 4; ++mt)                              \
            af[mt] = *(const bf16x8*)&As[(ABUF)][(wm * 64 + mt * 16 + l16) * 32 + quad * 8]; \
        _Pragma("unroll")                                           \
        for (int nt = 0; nt < 4; ++nt)                              \
            bfr[nt] = *(const bf16x8*)&Bs[(BBUF)][(wn * 64 + nt * 16 + l16) * 32 + quad * 8]; \
        __builtin_amdgcn_s_setprio(1);                              \
        _Pragma("unroll")                                           \
        for (int mt = 0; mt < 4; ++mt)                              \
            _Pragma("unroll")                                       \
            for (int nt = 0; nt < 4; ++nt)                          \
                acc[mt][nt] = __builtin_amdgcn_mfma_f32_16x16x32_bf16(af[mt], bfr[nt], \
                                                                      acc[mt][nt], 0, 0, 0); \
        __builtin_amdgcn_s_setprio(0);                              \
    } while (0)

    // prologue: B0,B1 issued; A0 written to LDS; A1,A2 in flight
    ISSUEB(0, 0);
    ISSUEB(32, 1);
    LOADA(0, 0);
    LOADA(32, 1);
    WRITEA(0, 0);                      // compiler waits A0 (vmcnt(4)): retires B0,B1 too
    LOADA(64, 2);
    asm volatile("s_waitcnt lgkmcnt(0)" ::: "memory");
    __builtin_amdgcn_s_barrier();

#define QSTEP(S) do {                                                          \
        if ((S) + 2 <= 31) ISSUEB(((S) + 2) * 32, ((S) + 2) % 3);              \
        COMPUTE((S) & 1, (S) % 3);                                             \
        if ((S) + 1 <= 31) WRITEA(((S) & 1) ^ 1, ((S) + 1) % 3);               \
        if ((S) + 3 <= 31) LOADA(((S) + 3) * 32, (S) % 3);                     \
        if ((S) <= 28) {                                                       \
            asm volatile("s_waitcnt vmcnt(10) lgkmcnt(0)" ::: "memory");       \
            __builtin_amdgcn_s_barrier();                                      \
        } else if ((S) == 29) {                                                \
            asm volatile("s_waitcnt vmcnt(6) lgkmcnt(0)" ::: "memory");        \
            __builtin_amdgcn_s_barrier();                                      \
        } else if ((S) == 30) {                                                \
            asm volatile("s_waitcnt vmcnt(0) lgkmcnt(0)" ::: "memory");        \
            __builtin_amdgcn_s_barrier();                                      \
        }                                                                      \
    } while (0);
#define QSTEP8(S) QSTEP(S) QSTEP((S)+1) QSTEP((S)+2) QSTEP((S)+3) \
                  QSTEP((S)+4) QSTEP((S)+5) QSTEP((S)+6) QSTEP((S)+7)
    QSTEP8(0) QSTEP8(8) QSTEP8(16) QSTEP8(24)
#undef QSTEP8
#undef QSTEP

    // epilogue: C/D layout col=lane&15, row=quad*4+reg
#pragma unroll
    for (int nt = 0; nt < 4; ++nt) {
        int col = n0 + wn * 64 + nt * 16 + l16;
        float bval = bias[col];
        int h = col >> 6, dp = col & 63;
#pragma unroll
        for (int mt = 0; mt < 4; ++mt) {
#pragma unroll
            for (int r = 0; r < 4; ++r) {
                int row = m0 + wm * 64 + mt * 16 + quad * 4 + r;
                float val = acc[mt][nt][r] + bval;
                int b = row >> 11, s = row & 2047;
                if (z == 0) {
                    Qh[(((size_t)(b * NHEAD + h)) * S_LEN + s) * DEPTH + dp] = f2bf(val);
                } else if (z == 1) {
                    if (s < nbv) {
                        int c2 = ((((dp >> 3) ^ (s & 7)) & 7) << 3) | (dp & 7);
                        Kc[(((size_t)(b * NHEAD + h)) * S_LEN + s) * DEPTH + c2] = f2bf(val);
                    }
                } else {
                    if (s < nbv) {
                        int off = s & 63;
                        int c1 = ((off & 15) << 2) | (off >> 4);                  // sigma
                        int c2 = ((((c1 >> 3) ^ (dp & 7)) & 7) << 3) | (c1 & 7);  // bank swz
                        Vc[(((size_t)(b * NHEAD + h)) * DEPTH + dp) * S_LEN
                           + (s & ~63) + c2] = f2bf(val);
                    }
                }
            }
        }
    }
#undef SEL
#undef LOADA
#undef WRITEA
#undef ISSUEB
#undef COMPUTE
}

// ---------------------------------------------------------------------------
// Out GEMM: d_out = ctx @ Wo^T + bo.  A bf16 head-split + B via async16,
// LDS tri-buffer both, depth-2 counted-vmcnt pipeline.
// ---------------------------------------------------------------------------
__global__ __launch_bounds__(256, 3)
void out_gemm(const uint16_t* __restrict__ ctx, const uint16_t* __restrict__ Wt,
              const float* __restrict__ bias, float* __restrict__ outp) {
    const int fid = blockIdx.x + 8 * blockIdx.y;
    const int n0 = ((fid >> 3) & 7) * 128;
    const int m0 = ((((fid >> 6) << 3)) | (fid & 7)) * 128;

    __shared__ __align__(16) uint16_t As[3][128 * 32];
    __shared__ __align__(16) uint16_t Bs[3][128 * 32];

    const int t = threadIdx.x;
    const int lane = t & 63, quad = lane >> 4, l16 = lane & 15;
    const int w = t >> 6, wm = w >> 1, wn = w & 1;
    const int K = DMODEL;

    const int r_ld = lane >> 2;
    const int c_ld = (lane & 3) * 8;
    const uint16_t* gB = Wt + (size_t)(n0 + r_ld) * K + c_ld;

    int row0 = m0 + (w * 2 + 0) * 16 + r_ld;
    int row1 = row0 + 16;
    const uint16_t* pA0 = ctx + ((size_t)((row0 >> 11) * NHEAD) * S_LEN + (row0 & 2047)) * DEPTH + c_ld;
    const uint16_t* pA1 = ctx + ((size_t)((row1 >> 11) * NHEAD) * S_LEN + (row1 & 2047)) * DEPTH + c_ld;

#define OSTAGE(KC, BUF) do {                                                    \
        async16(gB + (size_t)((w * 2 + 0) * 16) * K + (KC), &Bs[(BUF)][(w * 2 + 0) * 512]); \
        async16(gB + (size_t)((w * 2 + 1) * 16) * K + (KC), &Bs[(BUF)][(w * 2 + 1) * 512]); \
        size_t aoff_ = ((size_t)((KC) >> 6) << 17) + ((KC) & 63);               \
        async16(pA0 + aoff_, &As[(BUF)][(w * 2 + 0) * 512]);                    \
        async16(pA1 + aoff_, &As[(BUF)][(w * 2 + 1) * 512]);                    \
    } while (0)

    f32x4 acc[4][4];
    const f32x4 z4 = {0.f, 0.f, 0.f, 0.f};
#pragma unroll
    for (int mt = 0; mt < 4; ++mt)
#pragma unroll
        for (int nt = 0; nt < 4; ++nt) acc[mt][nt] = z4;

    OSTAGE(0, 0);
    OSTAGE(32, 1);
    asm volatile("s_waitcnt vmcnt(4) lgkmcnt(0)" ::: "memory");
    __builtin_amdgcn_s_barrier();

#define OSTEP(S) do {                                                          \
        {                                                                      \
            bf16x8 af[4], bfr[4];                                              \
            _Pragma("unroll")                                                  \
            for (int mt = 0; mt < 4; ++mt)                                     \
                af[mt] = *(const bf16x8*)&As[(S) % 3][(wm * 64 + mt * 16 + l16) * 32 + quad * 8]; \
            _Pragma("unroll")                                                  \
            for (int nt = 0; nt < 4; ++nt)                                     \
                bfr[nt] = *(const bf16x8*)&Bs[(S) % 3][(wn * 64 + nt * 16 + l16) * 32 + quad * 8]; \
            __builtin_amdgcn_s_setprio(1);                                     \
            _Pragma("unroll")                                                  \
            for (int mt = 0; mt < 4; ++mt)                                     \
                _Pragma("unroll")                                              \
                for (int nt = 0; nt < 4; ++nt)                                 \
                    acc[mt][nt] = __builtin_amdgcn_mfma_f32_16x16x32_bf16(af[mt], bfr[nt], \
                                                                          acc[mt][nt], 0, 0, 0); \
            __builtin_amdgcn_s_setprio(0);                                     \
        }                                                                      \
        if ((S) + 2 <= 31) OSTAGE(((S) + 2) * 32, ((S) + 2) % 3);              \
        if ((S) <= 29) {                                                       \
            asm volatile("s_waitcnt vmcnt(4) lgkmcnt(0)" ::: "memory");        \
            __builtin_amdgcn_s_barrier();                                      \
        } else if ((S) == 30) {                                                \
            asm volatile("s_waitcnt vmcnt(0) lgkmcnt(0)" ::: "memory");        \
            __builtin_amdgcn_s_barrier();                                      \
        }                                                                      \
    } while (0);
#define OSTEP8(S) OSTEP(S) OSTEP((S)+1) OSTEP((S)+2) OSTEP((S)+3) \
                  OSTEP((S)+4) OSTEP((S)+5) OSTEP((S)+6) OSTEP((S)+7)
    OSTEP8(0) OSTEP8(8) OSTEP8(16) OSTEP8(24)
#undef OSTEP8
#undef OSTEP
#undef OSTAGE

#pragma unroll
    for (int nt = 0; nt < 4; ++nt) {
        int col = n0 + wn * 64 + nt * 16 + l16;
        float bval = bias[col];
#pragma unroll
        for (int mt = 0; mt < 4; ++mt) {
#pragma unroll
            for (int r = 0; r < 4; ++r) {
                int row = m0 + wm * 64 + mt * 16 + quad * 4 + r;
                outp[(size_t)row * DMODEL + col] = acc[mt][nt][r] + bval;
            }
        }
    }
}

// ---------------------------------------------------------------------------
// Flash attention over COMPACTED keys, fixed-max softmax (m=12, exp2-domain).
// Grid (16 q-tiles, 64 bh), XCD-swizzled. 256 thr (4 waves), 32 q-rows/wave.
// LDS 41KB -> 3 blocks/CU. One __syncthreads per tile; prefetch in flight.
// ---------------------------------------------------------------------------
__global__ __launch_bounds__(256, 3)
void flash_attn(const uint16_t* __restrict__ Qh, const uint16_t* __restrict__ Kc,
                const uint16_t* __restrict__ Vc, const int* __restrict__ nb,
                uint16_t* __restrict__ ctx) {
    __shared__ __align__(16) uint16_t Ks[2][64 * 64];
    __shared__ __align__(16) uint16_t Vs[2][64 * 64];
    __shared__ __align__(16) uint16_t Ps[4][16 * 72];

    const int t = threadIdx.x;
    const int w = t >> 6, lane = t & 63, quad = lane >> 4, l16 = lane & 15;
    // XCD swizzle: 16 q-tiles sharing one bh's K/V land on one XCD (bijective)
    const int fid = blockIdx.x + 16 * blockIdx.y;                // 0..1023
    const int q0 = ((fid >> 3) & 15) * 128;
    const int bh = ((fid >> 7) << 3) | (fid & 7);
    const int b = bh >> 4;
    const int nbv = nb[b];
    const int ntiles = (nbv + 63) >> 6;

    const int srow8 = lane >> 3, scol8 = (lane & 7) * 8;
    const uint16_t* pKn = Kc + ((size_t)bh * S_LEN + w * 16 + srow8) * DEPTH + scol8;
    const uint16_t* pVn = Vc + ((size_t)bh * DEPTH + w * 16 + srow8) * S_LEN + scol8;
    uint16_t* dK0 = &Ks[0][w * 16 * 64];
    uint16_t* dK1 = &Ks[1][w * 16 * 64];
    uint16_t* dV0 = &Vs[0][w * 16 * 64];
    uint16_t* dV1 = &Vs[1][w * 16 * 64];

    bf16x8 aq[2][2];
#pragma unroll
    for (int mt = 0; mt < 2; ++mt)
#pragma unroll
        for (int kc = 0; kc < 2; ++kc)
            aq[mt][kc] = *(const bf16x8*)(Qh + ((size_t)bh * S_LEN + q0 + w * 32 + mt * 16 + l16) * DEPTH
                                          + kc * 32 + quad * 8);

    float lrow[2][4];
    f32x4 Oacc[2][4];
    const f32x4 z4 = {0.f, 0.f, 0.f, 0.f};
#pragma unroll
    for (int mt = 0; mt < 2; ++mt)
#pragma unroll
        for (int r = 0; r < 4; ++r) lrow[mt][r] = 0.f;
#pragma unroll
    for (int mt = 0; mt < 2; ++mt)
#pragma unroll
        for (int nt = 0; nt < 4; ++nt) Oacc[mt][nt] = z4;

    const float C2 = 0.18033688f;
    const float M2 = 17.312340f;
    const int swzk = l16 & 7;

    async16(pKn, dK0); async16(pKn + 8 * DEPTH, dK0 + 8 * 64);
    async16(pVn, dV0); async16(pVn + 8 * S_LEN, dV0 + 8 * 64);
    pKn += 64 * DEPTH; pVn += 64;
    __syncthreads();

    for (int kt = 0; kt < ntiles; ++kt) {
        const int cur = kt & 1;
        if (kt + 1 < ntiles) {
            uint16_t* dK = cur ? dK0 : dK1;
            uint16_t* dV = cur ? dV0 : dV1;
            async16(pKn, dK); async16(pKn + 8 * DEPTH, dK + 8 * 64);
            async16(pVn, dV); async16(pVn + 8 * S_LEN, dV + 8 * 64);
            pKn += 64 * DEPTH; pVn += 64;
        }
        const uint16_t* ksrc = cur ? &Ks[1][0] : &Ks[0][0];
        const uint16_t* vsrc = cur ? &Vs[1][0] : &Vs[0][0];
        const int k0 = kt * 64;

        float pen[4];
#pragma unroll
        for (int nt = 0; nt < 4; ++nt)
            pen[nt] = (k0 + nt * 16 + l16 < nbv) ? -M2 : -2e9f;

        f32x4 sacc[2][4];
#pragma unroll
        for (int mt = 0; mt < 2; ++mt)
#pragma unroll
            for (int nt = 0; nt < 4; ++nt) sacc[mt][nt] = z4;
        __builtin_amdgcn_s_setprio(1);
#pragma unroll
        for (int kc = 0; kc < 2; ++kc) {
#pragma unroll
            for (int nt = 0; nt < 4; ++nt) {
                bf16x8 bk = *(const bf16x8*)&ksrc[(nt * 16 + l16) * 64 + (((kc * 4 + quad) ^ swzk) << 3)];
#pragma unroll
                for (int mt = 0; mt < 2; ++mt)
                    sacc[mt][nt] = __builtin_amdgcn_mfma_f32_16x16x32_bf16(aq[mt][kc], bk,
                                                                           sacc[mt][nt], 0, 0, 0);
            }
        }
        __builtin_amdgcn_s_setprio(0);

        bf16x8 bvr[2][4];
#pragma unroll
        for (int kc = 0; kc < 2; ++kc)
#pragma unroll
            for (int nt = 0; nt < 4; ++nt)
                bvr[kc][nt] = *(const bf16x8*)&vsrc[(nt * 16 + l16) * 64 + (((kc * 4 + quad) ^ swzk) << 3)];

#pragma unroll
        for (int mt = 0; mt < 2; ++mt) {
#pragma unroll
            for (int r = 0; r < 4; ++r) {
                float p0 = EXP2F(fmaf(sacc[mt][0][r], C2, pen[0]));
                float p1 = EXP2F(fmaf(sacc[mt][1][r], C2, pen[1]));
                float p2 = EXP2F(fmaf(sacc[mt][2][r], C2, pen[2]));
                float p3 = EXP2F(fmaf(sacc[mt][3][r], C2, pen[3]));
                lrow[mt][r] += (p0 + p1) + (p2 + p3);
                u16x4 pk;
                pk[0] = f2bf(p0); pk[1] = f2bf(p1); pk[2] = f2bf(p2); pk[3] = f2bf(p3);
                *(u16x4*)&Ps[w][(quad * 4 + r) * 72 + l16 * 4] = pk;
            }
            __builtin_amdgcn_s_setprio(1);
#pragma unroll
            for (int kc = 0; kc < 2; ++kc) {
                bf16x8 ap = *(const bf16x8*)&Ps[w][l16 * 72 + kc * 32 + quad * 8];
#pragma unroll
                for (int nt = 0; nt < 4; ++nt)
                    Oacc[mt][nt] = __builtin_amdgcn_mfma_f32_16x16x32_bf16(ap, bvr[kc][nt],
                                                                           Oacc[mt][nt], 0, 0, 0);
            }
            __builtin_amdgcn_s_setprio(0);
        }
        __syncthreads();
    }

#pragma unroll
    for (int mt = 0; mt < 2; ++mt) {
#pragma unroll
        for (int r = 0; r < 4; ++r) {
            float rs = lrow[mt][r];
            rs += __shfl_xor(rs, 1);
            rs += __shfl_xor(rs, 2);
            rs += __shfl_xor(rs, 4);
            rs += __shfl_xor(rs, 8);
            float inv = 1.0f / rs;
            int srow = q0 + w * 32 + mt * 16 + quad * 4 + r;
            size_t base = ((size_t)bh * S_LEN + srow) * DEPTH;
#pragma unroll
            for (int nt = 0; nt < 4; ++nt)
                ctx[base + nt * 16 + l16] = f2bf(Oacc[mt][nt][r] * inv);
        }
    }
}

// ---------------------------------------------------------------------------
extern "C" void kernel_launch(void* const* d_in, const int* in_sizes, int n_in,
                              void* d_out, int out_size, void* d_ws, size_t ws_size,
                              hipStream_t stream) {
    const float* v    = (const float*)d_in[0];
    const float* k    = (const float*)d_in[1];
    const float* q    = (const float*)d_in[2];
    const float* mask = (const float*)d_in[3];
    const float* Wq   = (const float*)d_in[4];
    const float* bq   = (const float*)d_in[5];
    const float* Wk   = (const float*)d_in[6];
    const float* bk   = (const float*)d_in[7];
    const float* Wv   = (const float*)d_in[8];
    const float* bv   = (const float*)d_in[9];
    const float* Wo   = (const float*)d_in[10];
    const float* bo   = (const float*)d_in[11];

    // ws: WT4(8MB) + Qh(16MB) + gidx(32KB) + nb(16B) = ~24MB
    char* p = (char*)d_ws;
    uint16_t* WT4 = (uint16_t*)p; p += (size_t)4 * DMODEL * DMODEL * 2;
    uint16_t* Qh  = (uint16_t*)p; p += (size_t)64 * S_LEN * DEPTH * 2;
    int* gidx     = (int*)p;      p += (size_t)4 * S_LEN * 4;
    int* nb       = (int*)p;      p += 16;

    // Kc, Vc (16MB bf16 each) in d_out — dead before out_gemm writes f32 out
    uint16_t* Kc = (uint16_t*)d_out;
    uint16_t* Vc = Kc + (size_t)64 * S_LEN * DEPTH;

    mask_scan<<<4, 256, 0, stream>>>(mask, gidx, nb);
    transpose4<<<dim3(32, 32, 4), dim3(32, 8), 0, stream>>>(Wq, Wk, Wv, Wo, WT4);

    qkv_gemm<<<dim3(8, 64, 3), 256, 0, stream>>>(q, k, v, WT4, bq, bk, bv,
                                                 Qh, Kc, Vc, gidx, nb);
    zero_tails<<<64, 256, 0, stream>>>(nb, Kc, Vc);

    flash_attn<<<dim3(16, 64), 256, 0, stream>>>(Qh, Kc, Vc, nb, Qh /*ctx*/);

    out_gemm<<<dim3(8, 64), 256, 0, stream>>>(Qh, WT4 + (size_t)3 * DMODEL * DMODEL,
                                              bo, (float*)d_out);
}